// Round 5
// baseline (2487.726 us; speedup 1.0000x reference)
//
#include <hip/hip_runtime.h>
#include <cstdint>
#include <cstddef>

#define HID 1024
#define INP 512
#define BATCH 128
#define TSTEPS 256
#define NK16 96         // K/16 total (x: 0..31, h: 32..95)
#define HSLOTS 32       // h slot rotation depth (t mod 32)
#define NBLK_CHUNK 256  // persistent grid size (co-residency enforced by coop launch)
#define HSLOT ((size_t)64 * 4 * 2 * 512)   // ushorts per h slot (0.5 MB)

using short8  = __attribute__((ext_vector_type(8))) short;
using f32x16  = __attribute__((ext_vector_type(16))) float;

#define LD8(p) (*(const short8*)(p))
#define MFMA32(a,b,c) __builtin_amdgcn_mfma_f32_32x32x16_bf16((a),(b),(c),0,0,0)

static __device__ __forceinline__ unsigned short f2bf(float f) {
    union { float f; unsigned int u; } v; v.f = f;
    unsigned int r = v.u + 0x7fffu + ((v.u >> 16) & 1u);   // RNE
    return (unsigned short)(r >> 16);
}
static __device__ __forceinline__ float bf2f(unsigned short b) {
    union { unsigned int u; float f; } v; v.u = ((unsigned int)b) << 16;
    return v.f;
}
static __device__ __forceinline__ float sigmoid_f(float z) {
    return 1.0f / (1.0f + __expf(-z));
}
static __device__ __forceinline__ float tanh_f(float z) {
    return 2.0f / (1.0f + __expf(-2.0f * z)) - 1.0f;
}

// ---------------------------------------------------------------------------
// Fragment layouts (32x32x16 MFMA; verified):
//   A: lane l holds W[s*32 + (l&31)][k16*16 + (l>>5)*8 + e]
//      wfrag[s:128][k16:96][p:2][lane:64][e:8]   (p: 0=hi, 1=lo)
//   B: lane l holds act[col = cg*32 + (l&31)][k16*16 + (l>>5)*8 + e]
//      xfrag[t:256][k16:32][cg:4][p:2][lane:64][e:8]
//      hbuf[slot:32][k16:64][cg:4][p:2][lane:64][e:8]   (rotating slots)
//
// h transport: sc1 (agent-scope relaxed) stores -> MALL; readers use plain
// cached loads on 32-step-fresh addresses; one acquire fence per 32 steps
// covers slot reuse. Grid barrier: RMW-free monotonic per-block flags +
// parallel 256-flag sweep. Both proven in round 4.
//
// Round-5 changes: W-h slice lives in LDS (loaded once, 131 KB); W-x lives
// in 32 VGPRs; x-B fully prefetched; h-B 3-buffer 2-deep prefetch;
// K-reduce via part[3] 3-round tree (24 KB); gates scatter h directly.
// ---------------------------------------------------------------------------

// Prep 1: weights -> wfrag. Grid (96, 128) = (k16, s), 256 threads.
__global__ void prep_w(const float* __restrict__ Wgx, const float* __restrict__ Wix,
                       const float* __restrict__ Wfx, const float* __restrict__ Wox,
                       const float* __restrict__ Wgh, const float* __restrict__ Wih,
                       const float* __restrict__ Wfh, const float* __restrict__ Woh,
                       unsigned short* __restrict__ wfrag)
{
    const int k16 = blockIdx.x;        // 0..95
    const int s   = blockIdx.y;        // 0..127
    const int tid  = threadIdx.x;
    const int lane = tid >> 2;         // 0..63
    const int e0   = (tid & 3) * 2;    // 0,2,4,6
    const int row  = s * 32 + (lane & 31);
    const int k    = k16 * 16 + (lane >> 5) * 8 + e0;
    const int j = row >> 2;
    const int g = row & 3;
    float f0, f1;
    if (k < INP) {
        const float* wx = (g == 0 ? Wgx : g == 1 ? Wix : g == 2 ? Wfx : Wox) + (size_t)j * INP;
        f0 = wx[k]; f1 = wx[k + 1];
    } else {
        const float* wh = (g == 0 ? Wgh : g == 1 ? Wih : g == 2 ? Wfh : Woh) + (size_t)j * HID;
        f0 = wh[k - INP]; f1 = wh[k - INP + 1];
    }
    ushort2 hi, lo;
    hi.x = f2bf(f0); lo.x = f2bf(f0 - bf2f(hi.x));
    hi.y = f2bf(f1); lo.y = f2bf(f1 - bf2f(hi.y));
    unsigned short* base = wfrag + ((size_t)(s * NK16 + k16) * 2) * 512 + lane * 8 + e0;
    *(ushort2*)(base)       = hi;
    *(ushort2*)(base + 512) = lo;
}

// Prep 2: x -> xfrag. Grid (32, 256) = (k16x, t), 256 threads.
__global__ void prep_x(const float* __restrict__ x, unsigned short* __restrict__ xfrag)
{
    const int k16x = blockIdx.x;       // 0..31
    const int t    = blockIdx.y;       // 0..255
    const int tid  = threadIdx.x;
    const int cg   = tid >> 6;         // 0..3
    const int lane = tid & 63;
    const int col  = cg * 32 + (lane & 31);
    const int k0   = k16x * 16 + (lane >> 5) * 8;
    const float* src = x + ((size_t)col * TSTEPS + t) * INP + k0;
    const float4 v0 = *(const float4*)(src);
    const float4 v1 = *(const float4*)(src + 4);
    ushort4 h0, l0, h1, l1;
    h0.x = f2bf(v0.x); l0.x = f2bf(v0.x - bf2f(h0.x));
    h0.y = f2bf(v0.y); l0.y = f2bf(v0.y - bf2f(h0.y));
    h0.z = f2bf(v0.z); l0.z = f2bf(v0.z - bf2f(h0.z));
    h0.w = f2bf(v0.w); l0.w = f2bf(v0.w - bf2f(h0.w));
    h1.x = f2bf(v1.x); l1.x = f2bf(v1.x - bf2f(h1.x));
    h1.y = f2bf(v1.y); l1.y = f2bf(v1.y - bf2f(h1.y));
    h1.z = f2bf(v1.z); l1.z = f2bf(v1.z - bf2f(h1.z));
    h1.w = f2bf(v1.w); l1.w = f2bf(v1.w - bf2f(h1.w));
    unsigned short* base = xfrag +
        ((size_t)(((size_t)t * 32 + k16x) * 4 + cg) * 2) * 512 + lane * 8;
    *(ushort4*)(base)           = h0;
    *(ushort4*)(base + 4)       = h1;
    *(ushort4*)(base + 512)     = l0;
    *(ushort4*)(base + 512 + 4) = l1;
}

// Prep 3: c copy; h0 (H,B) -> hbuf slot 31 (initial h); zero flags.
__global__ void prep_state(const float* __restrict__ cin, const float* __restrict__ hin,
                           float* __restrict__ cdst, unsigned short* __restrict__ hslot,
                           unsigned* __restrict__ flags)
{
    if (blockIdx.x == 0) flags[threadIdx.x] = 0u;   // 256 flags (256 thr/blk)
    const int idx = blockIdx.x * 256 + threadIdx.x;   // 0..131071
    cdst[idx] = cin[idx];
    const int j = idx >> 7;
    const int b = idx & 127;
    float f = hin[idx];
    unsigned short hh = f2bf(f);
    unsigned short hl = f2bf(f - bf2f(hh));
    const int k16h = j >> 4;
    const int hlf  = (j >> 3) & 1;
    const int e    = j & 7;
    const int cg   = b >> 5;
    const int lane = 32 * hlf + (b & 31);
    unsigned short* base = hslot +
        ((size_t)((k16h * 4 + cg) * 2) * 512) + lane * 8 + e;
    base[0]   = hh;
    base[512] = hl;
}

// ---------------------------------------------------------------------------
// Persistent kernel: ALL 256 LSTM timesteps in ONE cooperative launch.
// ---------------------------------------------------------------------------
__global__ __launch_bounds__(512, 2) void lstm_persist(
    const unsigned short* __restrict__ wfrag,
    const unsigned short* __restrict__ xfrag,
    unsigned short* __restrict__ hbuf,
    float* __restrict__ cst,
    const float* __restrict__ bg, const float* __restrict__ bi,
    const float* __restrict__ bf_, const float* __restrict__ bo,
    float* __restrict__ outf,
    unsigned* __restrict__ flags)
{
    const int tid  = threadIdx.x;
    const int wv   = tid >> 6;             // K-slice 0..7
    const int lane = tid & 63;
    const int l31  = lane & 31;
    const int hl   = lane >> 5;
    const int bx   = blockIdx.x;

    const int xcd     = bx & 7;
    const int ii      = bx >> 3;
    const int s       = xcd * 16 + (ii >> 1);   // rowslice 0..127
    const int cb      = ii & 1;                 // col half
    const int colbase = cb << 6;

    // epilogue role: thread = (jloc = tid>>6, cl = tid&63)
    const int ejl  = tid >> 6;
    const int ecl  = tid & 63;
    const int ej   = s * 8 + ejl;
    const int ecol = colbase + ecl;
    const size_t ci = (size_t)ej * BATCH + ecol;

    const float bias0 = bg[ej], bias1 = bi[ej], bias2 = bf_[ej], bias3 = bo[ej];
    float creg = cst[ci];                    // c lives in a register all 256 steps

    const size_t bOff = (size_t)(4 * wv + 2 * cb) * 1024 + lane * 8;
    const int k16h = s >> 1;                 // h-scatter constant
    const int cgg   = (colbase >> 5) + (ecl >> 5);
    const int lane8 = 32 * (s & 1) + (ecl & 31);
    const size_t hscat = ((size_t)((k16h * 4 + cgg) * 2) * 512) + lane8 * 8 + ejl;

    // LDS: W-h slice (128 KiB) + 3-slot K-partial tree (24 KiB) = 152 KiB.
    __shared__ unsigned short WhLds[65536];
    __shared__ float part[3][32][64];

    // ---- prologue: W-h slice -> LDS (contiguous 131072 B region of wfrag)
    {
        const unsigned short* src = wfrag + (size_t)(s * NK16 + 32) * 2 * 512;
#pragma unroll
        for (int c = 0; c < 16; ++c) {
            const int cid = c * 512 + tid;
            *(short8*)(WhLds + (size_t)cid * 8) = LD8(src + (size_t)cid * 8);
        }
    }
    // ---- prologue: W-x slice -> 32 VGPRs (values stay live across the loop;
    // the memory-clobbered barriers below make re-loading illegal).
    short8 wxh[4], wxl[4];
    {
        const unsigned short* pWx = wfrag + ((size_t)(s * NK16 + wv) * 2) * 512 + lane * 8;
#pragma unroll
        for (int m = 0; m < 4; ++m) {
            wxh[m] = LD8(pWx);
            wxl[m] = LD8(pWx + 512);
            pWx += 8192;
        }
    }
    __syncthreads();

#pragma unroll 1
    for (int t = 0; t < TSTEPS; ++t) {
        f32x16 a0A, a0B, a1A, a1B;
#pragma unroll
        for (int r = 0; r < 16; ++r) { a0A[r]=0.f; a0B[r]=0.f; a1A[r]=0.f; a1B[r]=0.f; }

        // ---- x-part: all 16 B-loads issued upfront, then 24 MFMAs.
        {
            short8 xh0[4], xl0[4], xh1[4], xl1[4];
            const unsigned short* pX = xfrag + (size_t)t * 131072 + bOff;
#pragma unroll
            for (int m = 0; m < 4; ++m) {
                xh0[m] = LD8(pX);
                xl0[m] = LD8(pX + 512);
                xh1[m] = LD8(pX + 1024);
                xl1[m] = LD8(pX + 1536);
                pX += 32768;
            }
#pragma unroll
            for (int m = 0; m < 4; ++m) {
                a0A = MFMA32(wxh[m], xh0[m], a0A);
                a1A = MFMA32(wxh[m], xh1[m], a1A);
                a0B = MFMA32(wxh[m], xl0[m], a0B);
                a1B = MFMA32(wxh[m], xl1[m], a1B);
                a0A = MFMA32(wxl[m], xh0[m], a0A);
                a1A = MFMA32(wxl[m], xh1[m], a1A);
            }
        }

        // ---- flag sweep: wait until all 256 blocks finished step t-1.
        if (t > 0) {
            const unsigned target = (unsigned)t;
            int done;
            int guard = 0;
            do {
                unsigned v = target;
                if (tid < 256)
                    v = __hip_atomic_load(&flags[tid], __ATOMIC_RELAXED,
                                          __HIP_MEMORY_SCOPE_AGENT);
                done = __syncthreads_count(v >= target);
                if (done < 512) __builtin_amdgcn_s_sleep(1);
            } while (done < 512 && ++guard < (1 << 20));   // bounded: never hangs
            asm volatile("" ::: "memory");   // no hoisting h loads above sweep
            __builtin_amdgcn_sched_barrier(0);
            // periodic L1/L2 invalidate covering slot-address reuse (32-step
            // rotation). Placed after sweep (producers done), before h reads.
            if ((t & 31) == 0)
                __builtin_amdgcn_fence(__ATOMIC_ACQUIRE, "agent");
        }

        // ---- h-part: A from LDS, B 3-buffer rotate prefetched 2 m-iters ahead.
        {
            const unsigned short* pH = hbuf
                + (size_t)((t + HSLOTS - 1) & (HSLOTS - 1)) * HSLOT + bOff;
            short8 bh0[3], bl0[3], bh1[3], bl1[3];
#pragma unroll
            for (int i = 0; i < 2; ++i) {
                bh0[i] = LD8(pH);
                bl0[i] = LD8(pH + 512);
                bh1[i] = LD8(pH + 1024);
                bl1[i] = LD8(pH + 1536);
                pH += 32768;
            }
#pragma unroll
            for (int m = 0; m < 8; ++m) {
                const int cur = m % 3;
                const int nxt = (m + 2) % 3;
                if (m < 6) {
                    bh0[nxt] = LD8(pH);
                    bl0[nxt] = LD8(pH + 512);
                    bh1[nxt] = LD8(pH + 1024);
                    bl1[nxt] = LD8(pH + 1536);
                    pH += 32768;
                }
                const unsigned short* wp = WhLds + (size_t)((8 * m + wv) * 2) * 512 + lane * 8;
                short8 Ah = *(const short8*)(wp);
                short8 Al = *(const short8*)(wp + 512);
                a0A = MFMA32(Ah, bh0[cur], a0A);
                a1A = MFMA32(Ah, bh1[cur], a1A);
                a0B = MFMA32(Ah, bl0[cur], a0B);
                a1B = MFMA32(Ah, bl1[cur], a1B);
                a0A = MFMA32(Al, bh0[cur], a0A);
                a1A = MFMA32(Al, bh1[cur], a1A);
            }
        }

        // ---- K-partial tree reduce: 3 slots, 3 rounds.
        if (wv >= 5) {
#pragma unroll
            for (int r = 0; r < 16; ++r) {
                const int lr = (r & 3) + 8 * (r >> 2) + 4 * hl;
                part[wv - 5][lr][l31]      = a0A[r] + a0B[r];
                part[wv - 5][lr][32 + l31] = a1A[r] + a1B[r];
            }
        }
        __syncthreads();
        if (wv >= 2 && wv < 5) {
#pragma unroll
            for (int r = 0; r < 16; ++r) {
                const int lr = (r & 3) + 8 * (r >> 2) + 4 * hl;
                part[wv - 2][lr][l31]      += a0A[r] + a0B[r];
                part[wv - 2][lr][32 + l31] += a1A[r] + a1B[r];
            }
        }
        __syncthreads();
        if (wv < 2) {
#pragma unroll
            for (int r = 0; r < 16; ++r) {
                const int lr = (r & 3) + 8 * (r >> 2) + 4 * hl;
                part[wv][lr][l31]      += a0A[r] + a0B[r];
                part[wv][lr][32 + l31] += a1A[r] + a1B[r];
            }
        }
        __syncthreads();

        // ---- gates + direct h scatter (sc1 ushort stores; dense 512B runs).
        {
            unsigned short* hout = hbuf + (size_t)(t & (HSLOTS - 1)) * HSLOT;
            const int r0 = 4 * ejl;
            float z0g = bias0 + part[0][r0 + 0][ecl] + part[1][r0 + 0][ecl] + part[2][r0 + 0][ecl];
            float z1g = bias1 + part[0][r0 + 1][ecl] + part[1][r0 + 1][ecl] + part[2][r0 + 1][ecl];
            float z2g = bias2 + part[0][r0 + 2][ecl] + part[1][r0 + 2][ecl] + part[2][r0 + 2][ecl];
            float z3g = bias3 + part[0][r0 + 3][ecl] + part[1][r0 + 3][ecl] + part[2][r0 + 3][ecl];
            float gg = tanh_f(z0g);
            float ig = sigmoid_f(z1g);
            float fg = sigmoid_f(z2g);
            float og = sigmoid_f(z3g);
            float cn = gg * ig + creg * fg;
            creg = cn;
            float hh = tanh_f(cn) * og;
            unsigned short hb  = f2bf(hh);
            unsigned short hlo = f2bf(hh - bf2f(hb));
            __hip_atomic_store(hout + hscat, hb,
                               __ATOMIC_RELAXED, __HIP_MEMORY_SCOPE_AGENT);
            __hip_atomic_store(hout + hscat + 512, hlo,
                               __ATOMIC_RELAXED, __HIP_MEMORY_SCOPE_AGENT);
            if (outf && t == TSTEPS - 1) outf[ci] = hh;
        }

        // drain h stores to the coherence point, then raise our flag.
        asm volatile("s_waitcnt vmcnt(0)" ::: "memory");
        __syncthreads();
        if (tid == 0)
            __hip_atomic_store(&flags[bx], (unsigned)(t + 1),
                               __ATOMIC_RELAXED, __HIP_MEMORY_SCOPE_AGENT);
    }
    cst[ci] = creg;
}

// ---------------------------------------------------------------------------
// Fallback per-step kernel (used if coop launch unavailable or ws too small).
// ---------------------------------------------------------------------------
__global__ __launch_bounds__(512, 1) void lstm_step(
    const unsigned short* __restrict__ wfrag,
    const unsigned short* __restrict__ xfrag,
    const unsigned short* __restrict__ hin,
    unsigned short* __restrict__ hout,
    float* __restrict__ cst,
    const float* __restrict__ bg, const float* __restrict__ bi,
    const float* __restrict__ bf_, const float* __restrict__ bo,
    float* __restrict__ outf, int t)
{
    const int tid  = threadIdx.x;
    const int wv   = tid >> 6;
    const int lane = tid & 63;
    const int l31  = lane & 31;
    const int hl   = lane >> 5;
    const int bx   = blockIdx.x;

    const int xcd     = bx & 7;
    const int ii      = bx >> 3;
    const int s       = xcd * 16 + (ii >> 1);
    const int cb      = ii & 1;
    const int colbase = cb << 6;

    const int ejl  = tid >> 6;
    const int ecl  = tid & 63;
    const int ej   = s * 8 + ejl;
    const int ecol = colbase + ecl;

    float add0 = bg[ej], add1 = bi[ej], add2 = bf_[ej], add3 = bo[ej];
    const size_t ci = (size_t)ej * BATCH + ecol;
    float cold = cst[ci];

    f32x16 a0A, a0B, a1A, a1B;
#pragma unroll
    for (int r = 0; r < 16; ++r) { a0A[r]=0.f; a0B[r]=0.f; a1A[r]=0.f; a1B[r]=0.f; }

    const size_t bOff = (size_t)(4 * wv + 2 * cb) * 1024 + lane * 8;

    {
        const unsigned short* pA = wfrag + ((size_t)(s * NK16 + wv) * 2) * 512 + lane * 8;
        const unsigned short* pX = xfrag + (size_t)t * 131072 + bOff;
#pragma unroll
        for (int m = 0; m < 4; ++m) {
            short8 Ah  = LD8(pA);
            short8 Al  = LD8(pA + 512);
            short8 B0h = LD8(pX);
            short8 B0l = LD8(pX + 512);
            short8 B1h = LD8(pX + 1024);
            short8 B1l = LD8(pX + 1536);
            pA += 8192; pX += 32768;
            a0A = MFMA32(Ah, B0h, a0A);
            a1A = MFMA32(Ah, B1h, a1A);
            a0B = MFMA32(Ah, B0l, a0B);
            a1B = MFMA32(Ah, B1l, a1B);
            a0A = MFMA32(Al, B0h, a0A);
            a1A = MFMA32(Al, B1h, a1A);
        }
        const unsigned short* pH = hin + bOff;
#pragma unroll
        for (int m = 0; m < 8; ++m) {
            short8 Ah  = LD8(pA);
            short8 Al  = LD8(pA + 512);
            short8 B0h = LD8(pH);
            short8 B0l = LD8(pH + 512);
            short8 B1h = LD8(pH + 1024);
            short8 B1l = LD8(pH + 1536);
            pA += 8192; pH += 32768;
            a0A = MFMA32(Ah, B0h, a0A);
            a1A = MFMA32(Ah, B1h, a1A);
            a0B = MFMA32(Ah, B0l, a0B);
            a1B = MFMA32(Ah, B1l, a1B);
            a0A = MFMA32(Al, B0h, a0A);
            a1A = MFMA32(Al, B1h, a1A);
        }
    }

    __shared__ float part[8][32][64];
#pragma unroll
    for (int r = 0; r < 16; ++r) {
        const int lr = (r & 3) + 8 * (r >> 2) + 4 * hl;
        part[wv][lr][l31]      = a0A[r] + a0B[r];
        part[wv][lr][32 + l31] = a1A[r] + a1B[r];
    }
    __syncthreads();

    {
        const int r0 = 4 * ejl;
        float z0g = add0, z1g = add1, z2g = add2, z3g = add3;
#pragma unroll
        for (int p = 0; p < 8; ++p) {
            z0g += part[p][r0 + 0][ecl];
            z1g += part[p][r0 + 1][ecl];
            z2g += part[p][r0 + 2][ecl];
            z3g += part[p][r0 + 3][ecl];
        }
        float gg = tanh_f(z0g);
        float ig = sigmoid_f(z1g);
        float fg = sigmoid_f(z2g);
        float og = sigmoid_f(z3g);
        float cn = gg * ig + cold * fg;
        cst[ci] = cn;
        float hh = tanh_f(cn) * og;
        unsigned short hb  = f2bf(hh);
        unsigned short hlo = f2bf(hh - bf2f(hb));
        const int k16h  = s >> 1;
        const int cgg   = (colbase >> 5) + (ecl >> 5);
        const int lane8 = 32 * (s & 1) + (ecl & 31);
        unsigned short* dst = hout +
            ((size_t)((k16h * 4 + cgg) * 2) * 512) + lane8 * 8 + ejl;
        dst[0]   = hb;
        dst[512] = hlo;
        if (outf) outf[ci] = hh;
    }
}

// ---------------------------------------------------------------------------
extern "C" void kernel_launch(void* const* d_in, const int* in_sizes, int n_in,
                              void* d_out, int out_size, void* d_ws, size_t ws_size,
                              hipStream_t stream)
{
    const float* x   = (const float*)d_in[0];
    const float* c0v = (const float*)d_in[1];
    const float* h0v = (const float*)d_in[2];
    const float* Wgx = (const float*)d_in[3];
    const float* Wix = (const float*)d_in[4];
    const float* Wfx = (const float*)d_in[5];
    const float* Wox = (const float*)d_in[6];
    const float* Wgh = (const float*)d_in[7];
    const float* Wih = (const float*)d_in[8];
    const float* Wfh = (const float*)d_in[9];
    const float* Woh = (const float*)d_in[10];
    const float* bg  = (const float*)d_in[11];
    const float* bi  = (const float*)d_in[12];
    const float* bf  = (const float*)d_in[13];
    const float* bo  = (const float*)d_in[14];

    // ws layout (ushort unless noted):
    //   wfrag 25.2 MB | xfrag 67.1 MB | hbuf 32 x 0.5 MB = 16.8 MB
    //   cst 0.5 MB (f32) | flags 4 KB  => ~110 MB
    unsigned short* wfrag = (unsigned short*)d_ws;
    unsigned short* xfrag = wfrag + (size_t)128 * NK16 * 2 * 512;
    unsigned short* hbuf  = xfrag + (size_t)TSTEPS * 32 * 4 * 2 * 512;
    float* cst            = (float*)(hbuf + (size_t)HSLOTS * HSLOT);
    unsigned* flags       = (unsigned*)(cst + (size_t)HID * BATCH);

    const size_t needA = (size_t)((char*)(flags + 1024) - (char*)d_ws);
    const bool useA = (ws_size >= needA);

    float* outp = (float*)d_out;

    prep_w<<<dim3(NK16, 128), dim3(256), 0, stream>>>(Wgx, Wix, Wfx, Wox,
                                                      Wgh, Wih, Wfh, Woh, wfrag);
    prep_x<<<dim3(32, TSTEPS), dim3(256), 0, stream>>>(x, xfrag);
    prep_state<<<dim3(512), dim3(256), 0, stream>>>(c0v, h0v, cst,
                                                    hbuf + (size_t)(HSLOTS - 1) * HSLOT,
                                                    flags);

    bool done = false;
    if (useA) {
        // Cooperative launch: the runtime guarantees all 256 blocks are
        // co-resident (or returns an error instead of deadlocking).
        const unsigned short* a_wfrag = wfrag;
        const unsigned short* a_xfrag = xfrag;
        unsigned short* a_hbuf = hbuf;
        float* a_cst = cst;
        const float* a_bg = bg; const float* a_bi = bi;
        const float* a_bf = bf; const float* a_bo = bo;
        float* a_out = outp;
        unsigned* a_flags = flags;
        void* kargs[] = { (void*)&a_wfrag, (void*)&a_xfrag, (void*)&a_hbuf,
                          (void*)&a_cst, (void*)&a_bg, (void*)&a_bi,
                          (void*)&a_bf, (void*)&a_bo, (void*)&a_out,
                          (void*)&a_flags };
        hipError_t ce = hipLaunchCooperativeKernel(
            (const void*)lstm_persist, dim3(NBLK_CHUNK), dim3(512),
            kargs, 0, stream);
        done = (ce == hipSuccess);
    }

    if (!done) {
        // mode-B: per-step dispatches, h via slots 31/30, full K every step.
        unsigned short* hfA = hbuf + (size_t)(HSLOTS - 1) * HSLOT;  // initial h
        unsigned short* hfB = hbuf + (size_t)(HSLOTS - 2) * HSLOT;
        for (int t = 0; t < TSTEPS; ++t) {
            const unsigned short* hin = (t & 1) ? hfB : hfA;
            unsigned short* hout      = (t & 1) ? hfA : hfB;
            lstm_step<<<dim3(256), dim3(512), 0, stream>>>(
                wfrag, xfrag, hin, hout,
                cst, bg, bi, bf, bo,
                (t == TSTEPS - 1) ? outp : nullptr, t);
        }
    }
}

// Round 6
// 2159.980 us; speedup vs baseline: 1.1517x; 1.1517x over previous
//
#include <hip/hip_runtime.h>
#include <cstdint>
#include <cstddef>

#define HID 1024
#define INP 512
#define BATCH 128
#define TSTEPS 256
#define NK16 96         // K/16 total (x: 0..31, h: 32..95)
#define HSLOTS 32       // h slot rotation depth (t mod 32)
#define NBLK_CHUNK 256  // persistent grid size (co-residency enforced by coop launch)
#define HSLOT ((size_t)64 * 4 * 2 * 512)   // ushorts per h slot (0.5 MB)

using short8  = __attribute__((ext_vector_type(8))) short;
using f32x16  = __attribute__((ext_vector_type(16))) float;

#define LD8(p) (*(const short8*)(p))
#define MFMA32(a,b,c) __builtin_amdgcn_mfma_f32_32x32x16_bf16((a),(b),(c),0,0,0)

static __device__ __forceinline__ unsigned short f2bf(float f) {
    union { float f; unsigned int u; } v; v.f = f;
    unsigned int r = v.u + 0x7fffu + ((v.u >> 16) & 1u);   // RNE
    return (unsigned short)(r >> 16);
}
static __device__ __forceinline__ float bf2f(unsigned short b) {
    union { unsigned int u; float f; } v; v.u = ((unsigned int)b) << 16;
    return v.f;
}
static __device__ __forceinline__ float sigmoid_f(float z) {
    return 1.0f / (1.0f + __expf(-z));
}
static __device__ __forceinline__ float tanh_f(float z) {
    return 2.0f / (1.0f + __expf(-2.0f * z)) - 1.0f;
}

// ---------------------------------------------------------------------------
// Fragment layouts (32x32x16 MFMA; verified):
//   A: lane l holds W[s*32 + (l&31)][k16*16 + (l>>5)*8 + e]
//      wfrag[s:128][k16:96][p:2][lane:64][e:8]   (p: 0=hi, 1=lo)
//   B: lane l holds act[col = cg*32 + (l&31)][k16*16 + (l>>5)*8 + e]
//      xfrag[t:256][k16:32][cg:4][p:2][lane:64][e:8]
//      hbuf[slot:32][k16:64][cg:4][p:2][lane:64][e:8]   (rotating slots)
//
// h transport: sc1 (agent-scope relaxed) coalesced u64 stores -> MALL;
// readers use plain cached loads on 32-step-fresh addresses; one acquire
// fence per 32 steps covers slot reuse. Grid barrier: RMW-free monotonic
// per-block flags + parallel 256-flag sweep. All proven in round 4.
//
// Round-6 schedule: x-B prefetched into regs at end of previous step
// (completes under the sweep); after the sweep issue h-B half 1, run all
// x-MFMAs to cover that latency, issue h-B half 2, then run h-MFMAs with
// operands in flight. W-h in LDS (128 KB), W-x in 32 VGPRs.
// ---------------------------------------------------------------------------

// Prep 1: weights -> wfrag. Grid (96, 128) = (k16, s), 256 threads.
__global__ void prep_w(const float* __restrict__ Wgx, const float* __restrict__ Wix,
                       const float* __restrict__ Wfx, const float* __restrict__ Wox,
                       const float* __restrict__ Wgh, const float* __restrict__ Wih,
                       const float* __restrict__ Wfh, const float* __restrict__ Woh,
                       unsigned short* __restrict__ wfrag)
{
    const int k16 = blockIdx.x;        // 0..95
    const int s   = blockIdx.y;        // 0..127
    const int tid  = threadIdx.x;
    const int lane = tid >> 2;         // 0..63
    const int e0   = (tid & 3) * 2;    // 0,2,4,6
    const int row  = s * 32 + (lane & 31);
    const int k    = k16 * 16 + (lane >> 5) * 8 + e0;
    const int j = row >> 2;
    const int g = row & 3;
    float f0, f1;
    if (k < INP) {
        const float* wx = (g == 0 ? Wgx : g == 1 ? Wix : g == 2 ? Wfx : Wox) + (size_t)j * INP;
        f0 = wx[k]; f1 = wx[k + 1];
    } else {
        const float* wh = (g == 0 ? Wgh : g == 1 ? Wih : g == 2 ? Wfh : Woh) + (size_t)j * HID;
        f0 = wh[k - INP]; f1 = wh[k - INP + 1];
    }
    ushort2 hi, lo;
    hi.x = f2bf(f0); lo.x = f2bf(f0 - bf2f(hi.x));
    hi.y = f2bf(f1); lo.y = f2bf(f1 - bf2f(hi.y));
    unsigned short* base = wfrag + ((size_t)(s * NK16 + k16) * 2) * 512 + lane * 8 + e0;
    *(ushort2*)(base)       = hi;
    *(ushort2*)(base + 512) = lo;
}

// Prep 2: x -> xfrag. Grid (32, 256) = (k16x, t), 256 threads.
__global__ void prep_x(const float* __restrict__ x, unsigned short* __restrict__ xfrag)
{
    const int k16x = blockIdx.x;       // 0..31
    const int t    = blockIdx.y;       // 0..255
    const int tid  = threadIdx.x;
    const int cg   = tid >> 6;         // 0..3
    const int lane = tid & 63;
    const int col  = cg * 32 + (lane & 31);
    const int k0   = k16x * 16 + (lane >> 5) * 8;
    const float* src = x + ((size_t)col * TSTEPS + t) * INP + k0;
    const float4 v0 = *(const float4*)(src);
    const float4 v1 = *(const float4*)(src + 4);
    ushort4 h0, l0, h1, l1;
    h0.x = f2bf(v0.x); l0.x = f2bf(v0.x - bf2f(h0.x));
    h0.y = f2bf(v0.y); l0.y = f2bf(v0.y - bf2f(h0.y));
    h0.z = f2bf(v0.z); l0.z = f2bf(v0.z - bf2f(h0.z));
    h0.w = f2bf(v0.w); l0.w = f2bf(v0.w - bf2f(h0.w));
    h1.x = f2bf(v1.x); l1.x = f2bf(v1.x - bf2f(h1.x));
    h1.y = f2bf(v1.y); l1.y = f2bf(v1.y - bf2f(h1.y));
    h1.z = f2bf(v1.z); l1.z = f2bf(v1.z - bf2f(h1.z));
    h1.w = f2bf(v1.w); l1.w = f2bf(v1.w - bf2f(h1.w));
    unsigned short* base = xfrag +
        ((size_t)(((size_t)t * 32 + k16x) * 4 + cg) * 2) * 512 + lane * 8;
    *(ushort4*)(base)           = h0;
    *(ushort4*)(base + 4)       = h1;
    *(ushort4*)(base + 512)     = l0;
    *(ushort4*)(base + 512 + 4) = l1;
}

// Prep 3: c copy; h0 (H,B) -> hbuf slot 31 (initial h); zero flags.
__global__ void prep_state(const float* __restrict__ cin, const float* __restrict__ hin,
                           float* __restrict__ cdst, unsigned short* __restrict__ hslot,
                           unsigned* __restrict__ flags)
{
    if (blockIdx.x == 0) flags[threadIdx.x] = 0u;   // 256 flags (256 thr/blk)
    const int idx = blockIdx.x * 256 + threadIdx.x;   // 0..131071
    cdst[idx] = cin[idx];
    const int j = idx >> 7;
    const int b = idx & 127;
    float f = hin[idx];
    unsigned short hh = f2bf(f);
    unsigned short hl = f2bf(f - bf2f(hh));
    const int k16h = j >> 4;
    const int hlf  = (j >> 3) & 1;
    const int e    = j & 7;
    const int cg   = b >> 5;
    const int lane = 32 * hlf + (b & 31);
    unsigned short* base = hslot +
        ((size_t)((k16h * 4 + cg) * 2) * 512) + lane * 8 + e;
    base[0]   = hh;
    base[512] = hl;
}

// ---------------------------------------------------------------------------
// Persistent kernel: ALL 256 LSTM timesteps in ONE cooperative launch.
// ---------------------------------------------------------------------------
__global__ __launch_bounds__(512, 1) void lstm_persist(
    const unsigned short* __restrict__ wfrag,
    const unsigned short* __restrict__ xfrag,
    unsigned short* __restrict__ hbuf,
    float* __restrict__ cst,
    const float* __restrict__ bg, const float* __restrict__ bi,
    const float* __restrict__ bf_, const float* __restrict__ bo,
    float* __restrict__ outf,
    unsigned* __restrict__ flags)
{
    const int tid  = threadIdx.x;
    const int wv   = tid >> 6;             // K-slice 0..7
    const int lane = tid & 63;
    const int l31  = lane & 31;
    const int hl   = lane >> 5;
    const int bx   = blockIdx.x;

    const int xcd     = bx & 7;
    const int ii      = bx >> 3;
    const int s       = xcd * 16 + (ii >> 1);   // rowslice 0..127
    const int cb      = ii & 1;                 // col half
    const int colbase = cb << 6;

    // epilogue role: thread = (jloc = tid>>6, cl = tid&63)
    const int ejl  = tid >> 6;
    const int ecl  = tid & 63;
    const int ej   = s * 8 + ejl;
    const int ecol = colbase + ecl;
    const size_t ci = (size_t)ej * BATCH + ecol;

    const float bias0 = bg[ej], bias1 = bi[ej], bias2 = bf_[ej], bias3 = bo[ej];
    float creg = cst[ci];                    // c lives in a register all 256 steps

    const size_t bOff = (size_t)(4 * wv + 2 * cb) * 1024 + lane * 8;
    const int k16h = s >> 1;                 // h-store constant

    // LDS: W-h slice (128 KiB) + 3-slot K-partial tree (24 KiB) + hstage (2 KiB)
    __shared__ unsigned short WhLds[65536];
    __shared__ float part[3][32][64];
    __shared__ unsigned long long hstage[256];
    unsigned short* hs16 = (unsigned short*)hstage;

    // ---- prologue: W-h slice -> LDS (contiguous 131072 B region of wfrag)
    {
        const unsigned short* src = wfrag + (size_t)(s * NK16 + 32) * 2 * 512;
#pragma unroll
        for (int c = 0; c < 16; ++c) {
            const int cid = c * 512 + tid;
            *(short8*)(WhLds + (size_t)cid * 8) = LD8(src + (size_t)cid * 8);
        }
    }
    // ---- prologue: W-x slice -> 32 VGPRs (static across all steps)
    short8 wxh[4], wxl[4];
    {
        const unsigned short* pWx = wfrag + ((size_t)(s * NK16 + wv) * 2) * 512 + lane * 8;
#pragma unroll
        for (int m = 0; m < 4; ++m) {
            wxh[m] = LD8(pWx);
            wxl[m] = LD8(pWx + 512);
            pWx += 8192;
        }
    }
    // ---- prologue: x-B for t=0 -> 16 registers
    short8 xb0h[4], xb0l[4], xb1h[4], xb1l[4];
    {
        const unsigned short* pX = xfrag + bOff;
#pragma unroll
        for (int m = 0; m < 4; ++m) {
            xb0h[m] = LD8(pX);
            xb0l[m] = LD8(pX + 512);
            xb1h[m] = LD8(pX + 1024);
            xb1l[m] = LD8(pX + 1536);
            pX += 32768;
        }
    }
    __syncthreads();

#pragma unroll 1
    for (int t = 0; t < TSTEPS; ++t) {
        // ---- flag sweep: wait until all 256 blocks finished step t-1.
        // (Also drains the x-B prefetch issued at the end of step t-1.)
        if (t > 0) {
            const unsigned target = (unsigned)t;
            int done;
            int guard = 0;
            do {
                unsigned v = target;
                if (tid < 256)
                    v = __hip_atomic_load(&flags[tid], __ATOMIC_RELAXED,
                                          __HIP_MEMORY_SCOPE_AGENT);
                done = __syncthreads_count(v >= target);
                if (done < 512) __builtin_amdgcn_s_sleep(1);
            } while (done < 512 && ++guard < (1 << 20));   // bounded: never hangs
            asm volatile("" ::: "memory");   // no hoisting h loads above sweep
            __builtin_amdgcn_sched_barrier(0);
            // periodic L1/L2 invalidate covering slot-address reuse (32-step
            // rotation). Placed after sweep (producers done), before h reads.
            if ((t & 31) == 0)
                __builtin_amdgcn_fence(__ATOMIC_ACQUIRE, "agent");
        }

        f32x16 a0A, a0B, a1A, a1B;
#pragma unroll
        for (int r = 0; r < 16; ++r) { a0A[r]=0.f; a0B[r]=0.f; a1A[r]=0.f; a1B[r]=0.f; }

        const unsigned short* pH = hbuf
            + (size_t)((t + HSLOTS - 1) & (HSLOTS - 1)) * HSLOT + bOff;

        // ---- issue h-B half 1 (m=0..3): latency covered by x-MFMAs below.
        short8 hb0h[8], hb0l[8], hb1h[8], hb1l[8];
#pragma unroll
        for (int m = 0; m < 4; ++m) {
            hb0h[m] = LD8(pH);
            hb0l[m] = LD8(pH + 512);
            hb1h[m] = LD8(pH + 1024);
            hb1l[m] = LD8(pH + 1536);
            pH += 32768;
        }

        // ---- x-part: 24 MFMAs from registers (xb prefetched last step).
#pragma unroll
        for (int m = 0; m < 4; ++m) {
            a0A = MFMA32(wxh[m], xb0h[m], a0A);
            a1A = MFMA32(wxh[m], xb1h[m], a1A);
            a0B = MFMA32(wxh[m], xb0l[m], a0B);
            a1B = MFMA32(wxh[m], xb1l[m], a1B);
            a0A = MFMA32(wxl[m], xb0h[m], a0A);
            a1A = MFMA32(wxl[m], xb1h[m], a1A);
        }

        // ---- issue h-B half 2 (m=4..7): covered by h-MFMAs on half 1.
#pragma unroll
        for (int m = 4; m < 8; ++m) {
            hb0h[m] = LD8(pH);
            hb0l[m] = LD8(pH + 512);
            hb1h[m] = LD8(pH + 1024);
            hb1l[m] = LD8(pH + 1536);
            pH += 32768;
        }

        // ---- h-part: A from LDS, B from in-flight registers.
#pragma unroll
        for (int m = 0; m < 8; ++m) {
            const unsigned short* wp = WhLds + (size_t)((8 * m + wv) * 2) * 512 + lane * 8;
            short8 Ah = *(const short8*)(wp);
            short8 Al = *(const short8*)(wp + 512);
            a0A = MFMA32(Ah, hb0h[m], a0A);
            a1A = MFMA32(Ah, hb1h[m], a1A);
            a0B = MFMA32(Ah, hb0l[m], a0B);
            a1B = MFMA32(Ah, hb1l[m], a1B);
            a0A = MFMA32(Al, hb0h[m], a0A);
            a1A = MFMA32(Al, hb1h[m], a1A);
        }

        // ---- K-partial tree reduce: 3 slots, 3 rounds.
        if (wv >= 5) {
#pragma unroll
            for (int r = 0; r < 16; ++r) {
                const int lr = (r & 3) + 8 * (r >> 2) + 4 * hl;
                part[wv - 5][lr][l31]      = a0A[r] + a0B[r];
                part[wv - 5][lr][32 + l31] = a1A[r] + a1B[r];
            }
        }
        __syncthreads();
        if (wv >= 2 && wv < 5) {
#pragma unroll
            for (int r = 0; r < 16; ++r) {
                const int lr = (r & 3) + 8 * (r >> 2) + 4 * hl;
                part[wv - 2][lr][l31]      += a0A[r] + a0B[r];
                part[wv - 2][lr][32 + l31] += a1A[r] + a1B[r];
            }
        }
        __syncthreads();
        if (wv < 2) {
#pragma unroll
            for (int r = 0; r < 16; ++r) {
                const int lr = (r & 3) + 8 * (r >> 2) + 4 * hl;
                part[wv][lr][l31]      += a0A[r] + a0B[r];
                part[wv][lr][32 + l31] += a1A[r] + a1B[r];
            }
        }
        __syncthreads();

        // ---- gates: thread (ejl, ecl); stage h in LDS (coalescing).
        {
            const int r0 = 4 * ejl;
            float z0g = bias0 + part[0][r0 + 0][ecl] + part[1][r0 + 0][ecl] + part[2][r0 + 0][ecl];
            float z1g = bias1 + part[0][r0 + 1][ecl] + part[1][r0 + 1][ecl] + part[2][r0 + 1][ecl];
            float z2g = bias2 + part[0][r0 + 2][ecl] + part[1][r0 + 2][ecl] + part[2][r0 + 2][ecl];
            float z3g = bias3 + part[0][r0 + 3][ecl] + part[1][r0 + 3][ecl] + part[2][r0 + 3][ecl];
            float gg = tanh_f(z0g);
            float ig = sigmoid_f(z1g);
            float fg = sigmoid_f(z2g);
            float og = sigmoid_f(z3g);
            float cn = gg * ig + creg * fg;
            creg = cn;
            float hh = tanh_f(cn) * og;
            unsigned short hb  = f2bf(hh);
            unsigned short hlo = f2bf(hh - bf2f(hb));
            // LDS stage in output-region order: region r = (ecl>>5)*2 + p,
            // within-region ushort idx = (ecl&31)*8 + ejl.
            hs16[((ecl >> 5) * 2 + 0) * 256 + (ecl & 31) * 8 + ejl] = hb;
            hs16[((ecl >> 5) * 2 + 1) * 256 + (ecl & 31) * 8 + ejl] = hlo;
            if (outf && t == TSTEPS - 1) outf[ci] = hh;
        }
        __syncthreads();

        // ---- coalesced h store: 256 threads x u64, agent-scope (sc1 -> MALL).
        {
            unsigned short* hout = hbuf + (size_t)(t & (HSLOTS - 1)) * HSLOT;
            if (tid < 256) {
                const int r   = tid >> 6;
                const int w   = tid & 63;
                const int cgg = 2 * cb + (r >> 1);
                const int p   = r & 1;
                const size_t uo = ((size_t)((k16h * 4 + cgg) * 2 + p)) * 512
                                + 32 * (s & 1) * 8 + w * 4;
                __hip_atomic_store((unsigned long long*)(hout + uo), hstage[tid],
                                   __ATOMIC_RELAXED, __HIP_MEMORY_SCOPE_AGENT);
            }
        }
        // drain h stores to the coherence point, then raise our flag.
        asm volatile("s_waitcnt vmcnt(0)" ::: "memory");
        __syncthreads();
        if (tid == 0)
            __hip_atomic_store(&flags[bx], (unsigned)(t + 1),
                               __ATOMIC_RELAXED, __HIP_MEMORY_SCOPE_AGENT);

        // ---- prefetch x-B for step t+1 (flies during the next sweep).
        {
            const int tn = (t + 1 < TSTEPS) ? (t + 1) : t;
            const unsigned short* pX = xfrag + (size_t)tn * 131072 + bOff;
#pragma unroll
            for (int m = 0; m < 4; ++m) {
                xb0h[m] = LD8(pX);
                xb0l[m] = LD8(pX + 512);
                xb1h[m] = LD8(pX + 1024);
                xb1l[m] = LD8(pX + 1536);
                pX += 32768;
            }
        }
    }
    cst[ci] = creg;
}

// ---------------------------------------------------------------------------
// Fallback per-step kernel (used if coop launch unavailable or ws too small).
// ---------------------------------------------------------------------------
__global__ __launch_bounds__(512, 1) void lstm_step(
    const unsigned short* __restrict__ wfrag,
    const unsigned short* __restrict__ xfrag,
    const unsigned short* __restrict__ hin,
    unsigned short* __restrict__ hout,
    float* __restrict__ cst,
    const float* __restrict__ bg, const float* __restrict__ bi,
    const float* __restrict__ bf_, const float* __restrict__ bo,
    float* __restrict__ outf, int t)
{
    const int tid  = threadIdx.x;
    const int wv   = tid >> 6;
    const int lane = tid & 63;
    const int l31  = lane & 31;
    const int hl   = lane >> 5;
    const int bx   = blockIdx.x;

    const int xcd     = bx & 7;
    const int ii      = bx >> 3;
    const int s       = xcd * 16 + (ii >> 1);
    const int cb      = ii & 1;
    const int colbase = cb << 6;

    const int ejl  = tid >> 6;
    const int ecl  = tid & 63;
    const int ej   = s * 8 + ejl;
    const int ecol = colbase + ecl;

    float add0 = bg[ej], add1 = bi[ej], add2 = bf_[ej], add3 = bo[ej];
    const size_t ci = (size_t)ej * BATCH + ecol;
    float cold = cst[ci];

    f32x16 a0A, a0B, a1A, a1B;
#pragma unroll
    for (int r = 0; r < 16; ++r) { a0A[r]=0.f; a0B[r]=0.f; a1A[r]=0.f; a1B[r]=0.f; }

    const size_t bOff = (size_t)(4 * wv + 2 * cb) * 1024 + lane * 8;

    {
        const unsigned short* pA = wfrag + ((size_t)(s * NK16 + wv) * 2) * 512 + lane * 8;
        const unsigned short* pX = xfrag + (size_t)t * 131072 + bOff;
#pragma unroll
        for (int m = 0; m < 4; ++m) {
            short8 Ah  = LD8(pA);
            short8 Al  = LD8(pA + 512);
            short8 B0h = LD8(pX);
            short8 B0l = LD8(pX + 512);
            short8 B1h = LD8(pX + 1024);
            short8 B1l = LD8(pX + 1536);
            pA += 8192; pX += 32768;
            a0A = MFMA32(Ah, B0h, a0A);
            a1A = MFMA32(Ah, B1h, a1A);
            a0B = MFMA32(Ah, B0l, a0B);
            a1B = MFMA32(Ah, B1l, a1B);
            a0A = MFMA32(Al, B0h, a0A);
            a1A = MFMA32(Al, B1h, a1A);
        }
        const unsigned short* pH = hin + bOff;
#pragma unroll
        for (int m = 0; m < 8; ++m) {
            short8 Ah  = LD8(pA);
            short8 Al  = LD8(pA + 512);
            short8 B0h = LD8(pH);
            short8 B0l = LD8(pH + 512);
            short8 B1h = LD8(pH + 1024);
            short8 B1l = LD8(pH + 1536);
            pA += 8192; pH += 32768;
            a0A = MFMA32(Ah, B0h, a0A);
            a1A = MFMA32(Ah, B1h, a1A);
            a0B = MFMA32(Ah, B0l, a0B);
            a1B = MFMA32(Ah, B1l, a1B);
            a0A = MFMA32(Al, B0h, a0A);
            a1A = MFMA32(Al, B1h, a1A);
        }
    }

    __shared__ float part[8][32][64];
#pragma unroll
    for (int r = 0; r < 16; ++r) {
        const int lr = (r & 3) + 8 * (r >> 2) + 4 * hl;
        part[wv][lr][l31]      = a0A[r] + a0B[r];
        part[wv][lr][32 + l31] = a1A[r] + a1B[r];
    }
    __syncthreads();

    {
        const int r0 = 4 * ejl;
        float z0g = add0, z1g = add1, z2g = add2, z3g = add3;
#pragma unroll
        for (int p = 0; p < 8; ++p) {
            z0g += part[p][r0 + 0][ecl];
            z1g += part[p][r0 + 1][ecl];
            z2g += part[p][r0 + 2][ecl];
            z3g += part[p][r0 + 3][ecl];
        }
        float gg = tanh_f(z0g);
        float ig = sigmoid_f(z1g);
        float fg = sigmoid_f(z2g);
        float og = sigmoid_f(z3g);
        float cn = gg * ig + cold * fg;
        cst[ci] = cn;
        float hh = tanh_f(cn) * og;
        unsigned short hb  = f2bf(hh);
        unsigned short hlo = f2bf(hh - bf2f(hb));
        const int k16h  = s >> 1;
        const int cgg   = (colbase >> 5) + (ecl >> 5);
        const int lane8 = 32 * (s & 1) + (ecl & 31);
        unsigned short* dst = hout +
            ((size_t)((k16h * 4 + cgg) * 2) * 512) + lane8 * 8 + ejl;
        dst[0]   = hb;
        dst[512] = hlo;
        if (outf) outf[ci] = hh;
    }
}

// ---------------------------------------------------------------------------
extern "C" void kernel_launch(void* const* d_in, const int* in_sizes, int n_in,
                              void* d_out, int out_size, void* d_ws, size_t ws_size,
                              hipStream_t stream)
{
    const float* x   = (const float*)d_in[0];
    const float* c0v = (const float*)d_in[1];
    const float* h0v = (const float*)d_in[2];
    const float* Wgx = (const float*)d_in[3];
    const float* Wix = (const float*)d_in[4];
    const float* Wfx = (const float*)d_in[5];
    const float* Wox = (const float*)d_in[6];
    const float* Wgh = (const float*)d_in[7];
    const float* Wih = (const float*)d_in[8];
    const float* Wfh = (const float*)d_in[9];
    const float* Woh = (const float*)d_in[10];
    const float* bg  = (const float*)d_in[11];
    const float* bi  = (const float*)d_in[12];
    const float* bf  = (const float*)d_in[13];
    const float* bo  = (const float*)d_in[14];

    // ws layout (ushort unless noted):
    //   wfrag 25.2 MB | xfrag 67.1 MB | hbuf 32 x 0.5 MB = 16.8 MB
    //   cst 0.5 MB (f32) | flags 4 KB  => ~110 MB
    unsigned short* wfrag = (unsigned short*)d_ws;
    unsigned short* xfrag = wfrag + (size_t)128 * NK16 * 2 * 512;
    unsigned short* hbuf  = xfrag + (size_t)TSTEPS * 32 * 4 * 2 * 512;
    float* cst            = (float*)(hbuf + (size_t)HSLOTS * HSLOT);
    unsigned* flags       = (unsigned*)(cst + (size_t)HID * BATCH);

    const size_t needA = (size_t)((char*)(flags + 1024) - (char*)d_ws);
    const bool useA = (ws_size >= needA);

    float* outp = (float*)d_out;

    prep_w<<<dim3(NK16, 128), dim3(256), 0, stream>>>(Wgx, Wix, Wfx, Wox,
                                                      Wgh, Wih, Wfh, Woh, wfrag);
    prep_x<<<dim3(32, TSTEPS), dim3(256), 0, stream>>>(x, xfrag);
    prep_state<<<dim3(512), dim3(256), 0, stream>>>(c0v, h0v, cst,
                                                    hbuf + (size_t)(HSLOTS - 1) * HSLOT,
                                                    flags);

    bool done = false;
    if (useA) {
        // Cooperative launch: the runtime guarantees all 256 blocks are
        // co-resident (or returns an error instead of deadlocking).
        const unsigned short* a_wfrag = wfrag;
        const unsigned short* a_xfrag = xfrag;
        unsigned short* a_hbuf = hbuf;
        float* a_cst = cst;
        const float* a_bg = bg; const float* a_bi = bi;
        const float* a_bf = bf; const float* a_bo = bo;
        float* a_out = outp;
        unsigned* a_flags = flags;
        void* kargs[] = { (void*)&a_wfrag, (void*)&a_xfrag, (void*)&a_hbuf,
                          (void*)&a_cst, (void*)&a_bg, (void*)&a_bi,
                          (void*)&a_bf, (void*)&a_bo, (void*)&a_out,
                          (void*)&a_flags };
        hipError_t ce = hipLaunchCooperativeKernel(
            (const void*)lstm_persist, dim3(NBLK_CHUNK), dim3(512),
            kargs, 0, stream);
        done = (ce == hipSuccess);
    }

    if (!done) {
        // mode-B: per-step dispatches, h via slots 31/30, full K every step.
        unsigned short* hfA = hbuf + (size_t)(HSLOTS - 1) * HSLOT;  // initial h
        unsigned short* hfB = hbuf + (size_t)(HSLOTS - 2) * HSLOT;
        for (int t = 0; t < TSTEPS; ++t) {
            const unsigned short* hin = (t & 1) ? hfB : hfA;
            unsigned short* hout      = (t & 1) ? hfA : hfB;
            lstm_step<<<dim3(256), dim3(512), 0, stream>>>(
                wfrag, xfrag, hin, hout,
                cst, bg, bi, bf, bo,
                (t == TSTEPS - 1) ? outp : nullptr, t);
        }
    }
}